// Round 1
// baseline (1323.652 us; speedup 1.0000x reference)
//
#include <hip/hip_runtime.h>
#include <math.h>

#define N_NODES 100000
#define IN_DIM 64
#define HID 128
#define HID2 64
#define N_EDGES 1600000
#define BN_EPS 1e-5f

// ---------------------------------------------------------------------------
// Edge aggregation: one 64-lane wave per edge. lane i does
//   agg[dst][i] += feat[src][i]   (feature dim = 64)
// Optionally counts in-degree (once per edge, lane 0).
// ---------------------------------------------------------------------------
__global__ __launch_bounds__(256) void edge_agg64(
    const float* __restrict__ feat,   // [N,64]
    const int* __restrict__ src,      // [E]
    const int* __restrict__ dst,      // [E]
    float* __restrict__ agg,          // [N,64]
    float* __restrict__ cnt,          // [N] or nullptr
    int nEdges)
{
    int wave = (int)((blockIdx.x * (unsigned)blockDim.x + threadIdx.x) >> 6);
    int lane = threadIdx.x & 63;
    if (wave >= nEdges) return;
    int s = src[wave];
    int d = dst[wave];
    float v = feat[(size_t)s * 64 + lane];
    atomicAdd(&agg[(size_t)d * 64 + lane], v);
    if (cnt != nullptr && lane == 0) atomicAdd(&cnt[d], 1.0f);
}

// ---------------------------------------------------------------------------
// Layer-1 node kernel: one wave per node.
//   mean = agg1[n]/max(cnt,1)
//   pre[j] = mean . W1_l[:,j] + b1_l[j] + x[n] . W1_r[:,j]        (j=0..127)
//   h1[j]  = relu( (pre[j]-m1[j]) * g1[j]*rsqrt(v1[j]+eps) + be1[j] )
//   t1[c]  = h1 . W2_l[:,c]                                       (c=0..63)
// Lane l holds outputs j0=l, j1=l+64 of h1, and output c=l of t1.
// ---------------------------------------------------------------------------
__global__ __launch_bounds__(256) void node1_kernel(
    const float* __restrict__ x,      // [N,64]
    const float* __restrict__ agg1,   // [N,64]
    const float* __restrict__ cnt,    // [N]
    const float* __restrict__ W1l,    // [64,128]
    const float* __restrict__ b1l,    // [128]
    const float* __restrict__ W1r,    // [64,128]
    const float* __restrict__ g1, const float* __restrict__ be1,
    const float* __restrict__ m1, const float* __restrict__ v1,
    const float* __restrict__ W2l,    // [128,64]
    float* __restrict__ h1,           // [N,128]
    float* __restrict__ t1)           // [N,64]
{
    int node = (int)((blockIdx.x * (unsigned)blockDim.x + threadIdx.x) >> 6);
    int lane = threadIdx.x & 63;
    if (node >= N_NODES) return;

    float inv = 1.0f / fmaxf(cnt[node], 1.0f);
    float mv  = agg1[(size_t)node * 64 + lane] * inv;   // mean, lane-distributed
    float xv  = x[(size_t)node * 64 + lane];            // root feature

    const int j0 = lane, j1 = lane + 64;
    float acc0 = b1l[j0];
    float acc1 = b1l[j1];
    #pragma unroll
    for (int k = 0; k < 64; ++k) {
        float mk = __shfl(mv, k);
        float xk = __shfl(xv, k);
        acc0 = fmaf(mk, W1l[k * HID + j0], acc0);
        acc0 = fmaf(xk, W1r[k * HID + j0], acc0);
        acc1 = fmaf(mk, W1l[k * HID + j1], acc1);
        acc1 = fmaf(xk, W1r[k * HID + j1], acc1);
    }
    // BN (eval) + ReLU
    float s0 = g1[j0] * rsqrtf(v1[j0] + BN_EPS);
    float s1 = g1[j1] * rsqrtf(v1[j1] + BN_EPS);
    float h0 = fmaxf((acc0 - m1[j0]) * s0 + be1[j0], 0.0f);
    float h1v = fmaxf((acc1 - m1[j1]) * s1 + be1[j1], 0.0f);
    h1[(size_t)node * HID + j0] = h0;
    h1[(size_t)node * HID + j1] = h1v;

    // t1 = h1row @ W2_l   (pre-transform so layer-2 aggregation is 64-dim)
    float t = 0.0f;
    #pragma unroll
    for (int j = 0; j < 64; ++j) {
        float hj = __shfl(h0, j);
        t = fmaf(hj, W2l[j * HID2 + lane], t);
    }
    #pragma unroll
    for (int j = 0; j < 64; ++j) {
        float hj = __shfl(h1v, j);
        t = fmaf(hj, W2l[(j + 64) * HID2 + lane], t);
    }
    t1[(size_t)node * HID2 + lane] = t;
}

// ---------------------------------------------------------------------------
// Layer-2 node kernel + classifier: one wave per node.
//   pre[c] = agg2[n][c]/max(cnt,1) + b2_l[c] + h1[n] . W2_r[:,c]   (c=0..63)
//   h2[c]  = relu(bn2(pre[c]))
//   out[n] = h2 . Wc + bc     (2 logits, wave-reduced)
// ---------------------------------------------------------------------------
__global__ __launch_bounds__(256) void node2_kernel(
    const float* __restrict__ h1,     // [N,128]
    const float* __restrict__ agg2,   // [N,64]  (already W2_l-transformed sums)
    const float* __restrict__ cnt,    // [N]
    const float* __restrict__ b2l,    // [64]
    const float* __restrict__ W2r,    // [128,64]
    const float* __restrict__ g2, const float* __restrict__ be2,
    const float* __restrict__ m2, const float* __restrict__ v2,
    const float* __restrict__ Wc,     // [64,2]
    const float* __restrict__ bc,     // [2]
    float* __restrict__ out)          // [N,2]
{
    int node = (int)((blockIdx.x * (unsigned)blockDim.x + threadIdx.x) >> 6);
    int lane = threadIdx.x & 63;
    if (node >= N_NODES) return;

    float inv = 1.0f / fmaxf(cnt[node], 1.0f);
    float hlo = h1[(size_t)node * HID + lane];
    float hhi = h1[(size_t)node * HID + 64 + lane];

    float acc = agg2[(size_t)node * HID2 + lane] * inv + b2l[lane];
    #pragma unroll
    for (int j = 0; j < 64; ++j) {
        float hj = __shfl(hlo, j);
        acc = fmaf(hj, W2r[j * HID2 + lane], acc);
    }
    #pragma unroll
    for (int j = 0; j < 64; ++j) {
        float hj = __shfl(hhi, j);
        acc = fmaf(hj, W2r[(j + 64) * HID2 + lane], acc);
    }
    float s  = g2[lane] * rsqrtf(v2[lane] + BN_EPS);
    float h2 = fmaxf((acc - m2[lane]) * s + be2[lane], 0.0f);

    float l0 = h2 * Wc[lane * 2 + 0];
    float l1 = h2 * Wc[lane * 2 + 1];
    #pragma unroll
    for (int off = 32; off > 0; off >>= 1) {
        l0 += __shfl_xor(l0, off);
        l1 += __shfl_xor(l1, off);
    }
    if (lane == 0) {
        out[(size_t)node * 2 + 0] = l0 + bc[0];
        out[(size_t)node * 2 + 1] = l1 + bc[1];
    }
}

// ---------------------------------------------------------------------------
extern "C" void kernel_launch(void* const* d_in, const int* in_sizes, int n_in,
                              void* d_out, int out_size, void* d_ws, size_t ws_size,
                              hipStream_t stream)
{
    const float* x    = (const float*)d_in[0];
    const int*   eidx = (const int*)d_in[1];   // [2, E]: row 0 = src, row 1 = dst
    const float* W1l  = (const float*)d_in[2];
    const float* b1l  = (const float*)d_in[3];
    const float* W1r  = (const float*)d_in[4];
    const float* W2l  = (const float*)d_in[5];
    const float* b2l  = (const float*)d_in[6];
    const float* W2r  = (const float*)d_in[7];
    const float* g1   = (const float*)d_in[8];
    const float* be1  = (const float*)d_in[9];
    const float* m1   = (const float*)d_in[10];
    const float* v1   = (const float*)d_in[11];
    const float* g2   = (const float*)d_in[12];
    const float* be2  = (const float*)d_in[13];
    const float* m2   = (const float*)d_in[14];
    const float* v2   = (const float*)d_in[15];
    const float* Wc   = (const float*)d_in[16];
    const float* bc   = (const float*)d_in[17];
    float* out = (float*)d_out;

    // Workspace layout (bytes):
    //   cnt  : [0,                 400000)                 N floats
    //   agg1 : [400000,            400000+25.6M)           N*64  (reused as agg2)
    //   h1   : next N*128 floats
    //   t1   : next N*64  floats
    char* ws = (char*)d_ws;
    float* cnt  = (float*)ws;
    float* agg1 = (float*)(ws + (size_t)N_NODES * sizeof(float));
    float* h1   = agg1 + (size_t)N_NODES * 64;
    float* t1   = h1 + (size_t)N_NODES * HID;
    float* agg2 = agg1;  // agg1 is dead after node1_kernel

    const int* src = eidx;
    const int* dst = eidx + N_EDGES;

    const int edgeBlocks = (N_EDGES * 4 + 3) / 4;            // 4 edges per 256-thr block
    const int edgeGrid   = (N_EDGES + 3) / 4;
    const int nodeGrid   = (N_NODES + 3) / 4;
    (void)edgeBlocks;

    // zero cnt + agg1 (contiguous region)
    hipMemsetAsync(ws, 0, (size_t)N_NODES * sizeof(float) + (size_t)N_NODES * 64 * sizeof(float), stream);

    edge_agg64<<<edgeGrid, 256, 0, stream>>>(x, src, dst, agg1, cnt, N_EDGES);

    node1_kernel<<<nodeGrid, 256, 0, stream>>>(x, agg1, cnt, W1l, b1l, W1r,
                                               g1, be1, m1, v1, W2l, h1, t1);

    // zero agg2 (aliases agg1; safe — node1 already consumed agg1)
    hipMemsetAsync(agg2, 0, (size_t)N_NODES * 64 * sizeof(float), stream);

    edge_agg64<<<edgeGrid, 256, 0, stream>>>(t1, src, dst, agg2, nullptr, N_EDGES);

    node2_kernel<<<nodeGrid, 256, 0, stream>>>(h1, agg2, cnt, b2l, W2r,
                                               g2, be2, m2, v2, Wc, bc, out);
}